// Round 5
// baseline (384.194 us; speedup 1.0000x reference)
//
#include <hip/hip_runtime.h>

#define BB 32
#define L_MAXX 4096
#define DD 512
#define T_MAXX 2048

// Kernel 1: valid_len[b] = number of zero entries in padding_mask[b,:].
// Harness materializes the bool mask as int32 ("integer -> const int*"):
// 4096 int32 per batch = 16 KB. 256 threads x 4 int4 loads = 16 KB.
__global__ __launch_bounds__(256) void valid_len_kernel(
    const int* __restrict__ mask, int* __restrict__ vlen) {
    __shared__ int s;
    const int b = blockIdx.x;
    const int tid = threadIdx.x;
    if (tid == 0) s = 0;
    __syncthreads();
    const int4* m = reinterpret_cast<const int4*>(mask + (size_t)b * L_MAXX);
    int cnt = 0;
    #pragma unroll
    for (int j = 0; j < 4; ++j) {
        int4 v = m[tid + j * 256];
        cnt += (v.x != 0) + (v.y != 0) + (v.z != 0) + (v.w != 0);
    }
    atomicAdd(&s, cnt);
    __syncthreads();
    if (tid == 0) vlen[b] = L_MAXX - s;   // count of valid (False) positions
}

// Kernel 2: one block = 2 output rows t; 128 lanes x float4 = D=512 floats.
__global__ __launch_bounds__(256) void area_resample_kernel(
    const float* __restrict__ x,
    const int* __restrict__ finallength,
    const int* __restrict__ vlen,
    float* __restrict__ out,
    float* __restrict__ out_mask) {
    const int blk = blockIdx.x;
    const int b = blk >> 10;                               // 1024 blocks per batch (T_MAX/2)
    const int t = ((blk & 1023) << 1) | (threadIdx.x >> 7);
    const int lane = threadIdx.x & 127;

    const int T = finallength[b];
    const int L = vlen[b];

    float4 acc = make_float4(0.f, 0.f, 0.f, 0.f);
    float inv = 0.f;
    if (t < T) {
        const unsigned uT = (unsigned)T, uL = (unsigned)L;
        const unsigned start = ((unsigned)t * uL) / uT;
        const unsigned end   = ((unsigned)(t + 1) * uL + uT - 1u) / uT;  // ceil
        unsigned cnt = end - start;
        if (cnt < 1u) cnt = 1u;
        const float4* row =
            reinterpret_cast<const float4*>(x + ((size_t)b * L_MAXX + start) * DD) + lane;
        for (unsigned r = start; r < end; ++r) {
            float4 v = *row;
            acc.x += v.x; acc.y += v.y; acc.z += v.z; acc.w += v.w;
            row += DD / 4;
        }
        inv = 1.0f / (float)cnt;
    }
    float4 o = make_float4(acc.x * inv, acc.y * inv, acc.z * inv, acc.w * inv);
    reinterpret_cast<float4*>(out + ((size_t)b * T_MAXX + t) * DD)[lane] = o;
    if (lane == 0) {
        out_mask[(size_t)b * T_MAXX + t] = (t < T) ? 0.0f : 1.0f;
    }
}

extern "C" void kernel_launch(void* const* d_in, const int* in_sizes, int n_in,
                              void* d_out, int out_size, void* d_ws, size_t ws_size,
                              hipStream_t stream) {
    const float* x = (const float*)d_in[0];
    const int* finallength = (const int*)d_in[1];
    const int* mask = (const int*)d_in[2];
    // d_in[3] = max_out_len scalar (always 2048 here) — compiled in as T_MAXX.

    float* out = (float*)d_out;
    float* out_mask = out + (size_t)BB * T_MAXX * DD;
    int* vlen = (int*)d_ws;

    valid_len_kernel<<<BB, 256, 0, stream>>>(mask, vlen);
    area_resample_kernel<<<BB * (T_MAXX / 2), 256, 0, stream>>>(
        x, finallength, vlen, out, out_mask);
}